// Round 16
// baseline (95.296 us; speedup 1.0000x reference)
//
#include <hip/hip_runtime.h>
#include <hip/hip_bf16.h>

typedef __attribute__((ext_vector_type(4))) float          f32x4;
typedef __attribute__((ext_vector_type(4))) int            i32x4;
typedef __attribute__((ext_vector_type(2))) unsigned int   u32x2;
typedef __attribute__((ext_vector_type(4))) unsigned int   u32x4;
typedef __attribute__((ext_vector_type(8))) unsigned short u16x8;

#define Cc 512
#define Vv 512
#define BM 64

#define BOUND 0.04419417382415922f           /* 1/sqrt(512) — torch Linear init bound */
#define INV_SW (127.0f / BOUND)
#define OSCALE (BOUND / 16129.0f)            /* BOUND / (127*127) */

// W2i: i8 W in 16x16x64-MFMA B-fragment order.
// (v,k) -> frag (v>>4)*8 + (k>>6); lane (v&15)+16*((k>>4)&3); byte k&15
__device__ unsigned g_W2i[Vv * Cc / 4];      // uint array -> 16B-aligned
// bf16 tanh tables (L2-resident per XCD)
__device__ unsigned short g_ta[1600 * Cc];
__device__ unsigned short g_tp[400 * Cc];

__device__ __forceinline__ float fast_tanh(float x) {
    float e = __expf(2.0f * x);
    return 1.0f - 2.0f * __builtin_amdgcn_rcpf(e + 1.0f);
}

__device__ __forceinline__ unsigned cvt_pk_bf16(float lo, float hi) {
    unsigned r;
    asm("v_cvt_pk_bf16_f32 %0, %1, %2" : "=v"(r) : "v"(lo), "v"(hi));
    return r;
}

__device__ __forceinline__ float bf2f(unsigned short b) {
    return __uint_as_float(((unsigned)b) << 16);
}

__device__ __forceinline__ unsigned pack4(int q0, int q1, int q2, int q3) {
    return (q0 & 0xff) | ((q1 & 0xff) << 8) | ((q2 & 0xff) << 16) | (q3 << 24);
}

// blocks [0,64) -> W2i quant+swizzle; [64,464) -> tanh(enc) bf16; [464,564) -> tanh(pred) bf16
__global__ __launch_bounds__(256) void prep_kernel(
    const float* __restrict__ W, const float* __restrict__ enc,
    const float* __restrict__ pred)
{
    const int b = blockIdx.x;
    if (b < 64) {
        int gid = b * 256 + threadIdx.x;     // 0..16383, 16 k-elems each
        int v  = gid >> 5;
        int k0 = (gid & 31) * 16;
        const float* wp = W + v * Cc + k0;
        f32x4 wv[4];
#pragma unroll
        for (int c = 0; c < 4; ++c) wv[c] = *(const f32x4*)(wp + c * 4);
        u32x4 o;
#pragma unroll
        for (int c = 0; c < 4; ++c)
            o[c] = pack4(__float2int_rn(wv[c][0] * INV_SW),
                         __float2int_rn(wv[c][1] * INV_SW),
                         __float2int_rn(wv[c][2] * INV_SW),
                         __float2int_rn(wv[c][3] * INV_SW));
        int f  = (v >> 4) * 8 + (k0 >> 6);
        int ln = (v & 15) + 16 * ((k0 >> 4) & 3);
        *(u32x4*)((char*)g_W2i + f * 1024 + ln * 16) = o;
    } else if (b < 464) {
        int gid = (b - 64) * 256 + threadIdx.x;     // 8 elems each
        f32x4 a = *(const f32x4*)(enc + gid * 8);
        f32x4 c = *(const f32x4*)(enc + gid * 8 + 4);
        u32x4 o;
        o[0] = cvt_pk_bf16(fast_tanh(a[0]), fast_tanh(a[1]));
        o[1] = cvt_pk_bf16(fast_tanh(a[2]), fast_tanh(a[3]));
        o[2] = cvt_pk_bf16(fast_tanh(c[0]), fast_tanh(c[1]));
        o[3] = cvt_pk_bf16(fast_tanh(c[2]), fast_tanh(c[3]));
        *(u32x4*)(g_ta + gid * 8) = o;
    } else {
        int gid = (b - 464) * 256 + threadIdx.x;
        f32x4 a = *(const f32x4*)(pred + gid * 8);
        f32x4 c = *(const f32x4*)(pred + gid * 8 + 4);
        u32x4 o;
        o[0] = cvt_pk_bf16(fast_tanh(a[0]), fast_tanh(a[1]));
        o[1] = cvt_pk_bf16(fast_tanh(a[2]), fast_tanh(a[3]));
        o[2] = cvt_pk_bf16(fast_tanh(c[0]), fast_tanh(c[1]));
        o[3] = cvt_pk_bf16(fast_tanh(c[2]), fast_tanh(c[3]));
        *(u32x4*)(g_tp + gid * 8) = o;
    }
}

// Grid 2756, duration-staggered:
//   bids [0,256):      TOP half (rows 0..31) of tiles 0..255   (short blocks, fill slot 0)
//   bids [256,2500):   full tiles 256..2499                     (normal blocks, fill slot 1+)
//   bids [2500,2756):  BOTTOM half (rows 32..63) of tiles 0..255 (short blocks, dispatched last)
// Slot 0 of each CU finishes its short block ~0.45 epoch early and stays
// anti-phased with slot 1 thereafter: stage/compute hides under sibling drain.
__global__ __launch_bounds__(512, 4) void joiner_main(
    const float* __restrict__ bias,  // (512,)
    float* __restrict__ out)         // (160000, 512)
{
    __shared__ unsigned char As[BM * Cc];    // 32 KB i8 tile, XOR-swizzled rows

    const int tid = threadIdx.x;
    const int bid = blockIdx.x;

    int tile, r0, NI;
    if (bid < 256) {
        tile = (bid & 7) * 32 + (bid >> 3);  r0 = 0;  NI = 2;
    } else if (bid < 2500) {
        int x = bid - 256, c = x & 7, i2 = x >> 3;
        tile = 256 + (c < 4 ? c * 281 : 1124 + (c - 4) * 280) + i2;
        r0 = 0;  NI = 4;
    } else {
        int x = bid - 2500;
        tile = (x & 7) * 32 + (x >> 3);  r0 = 32;  NI = 2;
    }

    // ---- stage: A = q127(tanh-sum(ta,tp)) from bf16 tables -> i8 LDS ----
    if (NI == 4) {
        const int r = tid >> 3;          // 0..63
        const int q = tid & 7;
        const int m  = tile * BM + r;
        const int et = m / 100;
        const int u  = m - et * 100;
        const int bb = m / 40000;
        const int pr = bb * 100 + u;
        const unsigned short* taP = g_ta + et * Cc;
        const unsigned short* tpP = g_tp + pr * Cc;
        char* asB = (char*)As;
        const int swz = (r & 7) << 4;
#pragma unroll
        for (int c = 0; c < 8; ++c) {
            const int k0 = q * 8 + c * 64;
            u16x8 ta8 = *(const u16x8*)(taP + k0);
            u16x8 tp8 = *(const u16x8*)(tpP + k0);
            int qq[8];
#pragma unroll
            for (int j = 0; j < 8; ++j) {
                float a = bf2f(ta8[j]);
                float p = bf2f(tp8[j]);
                float n = (a + p) *
                          __builtin_amdgcn_rcpf(__builtin_fmaf(a, p, 1.0f));
                qq[j] = __float2int_rn(n * 127.0f);
            }
            u32x2 o;
            o[0] = pack4(qq[0], qq[1], qq[2], qq[3]);
            o[1] = pack4(qq[4], qq[5], qq[6], qq[7]);
            int byte = r * 512 + k0;
            *(u32x2*)(asB + (byte ^ swz)) = o;
        }
    } else {
        const int r = tid >> 4;          // 0..31
        const int q = tid & 15;
        const int m  = tile * BM + r0 + r;
        const int et = m / 100;
        const int u  = m - et * 100;
        const int bb = m / 40000;
        const int pr = bb * 100 + u;
        const unsigned short* taP = g_ta + et * Cc;
        const unsigned short* tpP = g_tp + pr * Cc;
        char* asB = (char*)As;
        const int swz = (r & 7) << 4;
#pragma unroll
        for (int c = 0; c < 4; ++c) {
            const int k0 = q * 8 + c * 128;
            u16x8 ta8 = *(const u16x8*)(taP + k0);
            u16x8 tp8 = *(const u16x8*)(tpP + k0);
            int qq[8];
#pragma unroll
            for (int j = 0; j < 8; ++j) {
                float a = bf2f(ta8[j]);
                float p = bf2f(tp8[j]);
                float n = (a + p) *
                          __builtin_amdgcn_rcpf(__builtin_fmaf(a, p, 1.0f));
                qq[j] = __float2int_rn(n * 127.0f);
            }
            u32x2 o;
            o[0] = pack4(qq[0], qq[1], qq[2], qq[3]);
            o[1] = pack4(qq[4], qq[5], qq[6], qq[7]);
            int byte = r * 512 + k0;
            *(u32x2*)(asB + (byte ^ swz)) = o;
        }
    }

    // ---- compute setup; first B-fragments primed BEFORE the barrier ----
    const int lane = tid & 63;
    const int w    = tid >> 6;          // wave -> V slice [w*64, (w+1)*64)
    const int lc   = lane & 15;
    const int lkB  = (lane >> 4) << 4;  // k-byte offset within 64-k step

    // B-fragment stream: frag (w*4 + j)*8 + ks, 1KB each
    const char* wb = (const char*)g_W2i + (size_t)(w * 4) * 8 * 1024 + lane * 16;

    i32x4 bcur[4], bnx[4];
#pragma unroll
    for (int j = 0; j < 4; ++j)
        bcur[j] = *(const i32x4*)(wb + ((j * 8 + 0) << 10));

    __syncthreads();   // only barrier

    i32x4 acc[4][4];
#pragma unroll
    for (int i = 0; i < 4; ++i)
#pragma unroll
        for (int j = 0; j < 4; ++j)
            acc[i][j] = (i32x4){0, 0, 0, 0};

    const char* asB = (const char*)As;
    const int aswz = (lc & 7) << 4;

#pragma unroll 2
    for (int ks = 0; ks < 8; ++ks) {
        if (ks < 7) {
#pragma unroll
            for (int j = 0; j < 4; ++j)
                bnx[j] = *(const i32x4*)(wb + ((j * 8 + ks + 1) << 10));
        }
        i32x4 af[4];
#pragma unroll
        for (int i = 0; i < 4; ++i) {
            if (i < NI) {
                int byte = (i * 16 + lc) * 512 + ks * 64 + lkB;
                af[i] = *(const i32x4*)(asB + (byte ^ aswz));
            }
        }
#pragma unroll
        for (int i = 0; i < 4; ++i) {
            if (i < NI) {
#pragma unroll
                for (int j = 0; j < 4; ++j)
                    acc[i][j] = __builtin_amdgcn_mfma_i32_16x16x64_i8(
                        af[i], bcur[j], acc[i][j], 0, 0, 0);
            }
        }
#pragma unroll
        for (int j = 0; j < 4; ++j) bcur[j] = bnx[j];
    }

    // ---- epilogue: C/D layout col=lane&15, row=(lane>>4)*4+q; dequant + bias ----
    const int lr = (lane >> 4) << 2;
    float bia[4];
#pragma unroll
    for (int j = 0; j < 4; ++j) bia[j] = bias[w * 64 + j * 16 + lc];
#pragma unroll
    for (int i = 0; i < 4; ++i) {
        if (i < NI) {
#pragma unroll
            for (int q = 0; q < 4; ++q) {
                size_t row = (size_t)(tile * BM + r0 + i * 16 + lr + q);
                float* op = out + row * Vv + w * 64;
#pragma unroll
                for (int j = 0; j < 4; ++j)
                    __builtin_nontemporal_store(
                        __builtin_fmaf((float)acc[i][j][q], OSCALE, bia[j]),
                        op + j * 16 + lc);
            }
        }
    }
}

extern "C" void kernel_launch(void* const* d_in, const int* in_sizes, int n_in,
                              void* d_out, int out_size, void* d_ws, size_t ws_size,
                              hipStream_t stream) {
    const float* enc  = (const float*)d_in[0];
    const float* pred = (const float*)d_in[1];
    const float* W    = (const float*)d_in[2];
    const float* bias = (const float*)d_in[3];
    float* out        = (float*)d_out;

    prep_kernel<<<564, 256, 0, stream>>>(W, enc, pred);
    joiner_main<<<2756, 512, 0, stream>>>(bias, out);
}

// Round 17
// 91.267 us; speedup vs baseline: 1.0441x; 1.0441x over previous
//
#include <hip/hip_runtime.h>
#include <hip/hip_bf16.h>

typedef __attribute__((ext_vector_type(4))) float          f32x4;
typedef __attribute__((ext_vector_type(4))) int            i32x4;
typedef __attribute__((ext_vector_type(2))) unsigned int   u32x2;
typedef __attribute__((ext_vector_type(4))) unsigned int   u32x4;
typedef __attribute__((ext_vector_type(8))) unsigned short u16x8;

#define Cc 512
#define Vv 512
#define BM 64
#define NTILE 2500

#define BOUND 0.04419417382415922f           /* 1/sqrt(512) — torch Linear init bound */
#define INV_SW (127.0f / BOUND)
#define OSCALE (BOUND / 16129.0f)            /* BOUND / (127*127) */

// W2i: i8 W in 16x16x64-MFMA B-fragment order.
// (v,k) -> frag (v>>4)*8 + (k>>6); lane (v&15)+16*((k>>4)&3); byte k&15
__device__ unsigned g_W2i[Vv * Cc / 4];      // uint array -> 16B-aligned
// bf16 tanh tables (L2-resident per XCD)
__device__ unsigned short g_ta[1600 * Cc];
__device__ unsigned short g_tp[400 * Cc];

__device__ __forceinline__ float fast_tanh(float x) {
    float e = __expf(2.0f * x);
    return 1.0f - 2.0f * __builtin_amdgcn_rcpf(e + 1.0f);
}

__device__ __forceinline__ unsigned cvt_pk_bf16(float lo, float hi) {
    unsigned r;
    asm("v_cvt_pk_bf16_f32 %0, %1, %2" : "=v"(r) : "v"(lo), "v"(hi));
    return r;
}

__device__ __forceinline__ float bf2f(unsigned short b) {
    return __uint_as_float(((unsigned)b) << 16);
}

__device__ __forceinline__ unsigned pack4(int q0, int q1, int q2, int q3) {
    return (q0 & 0xff) | ((q1 & 0xff) << 8) | ((q2 & 0xff) << 16) | (q3 << 24);
}

// blocks [0,64) -> W2i quant+swizzle; [64,464) -> tanh(enc) bf16; [464,564) -> tanh(pred) bf16
__global__ __launch_bounds__(256) void prep_kernel(
    const float* __restrict__ W, const float* __restrict__ enc,
    const float* __restrict__ pred)
{
    const int b = blockIdx.x;
    if (b < 64) {
        int gid = b * 256 + threadIdx.x;     // 0..16383, 16 k-elems each
        int v  = gid >> 5;
        int k0 = (gid & 31) * 16;
        const float* wp = W + v * Cc + k0;
        f32x4 wv[4];
#pragma unroll
        for (int c = 0; c < 4; ++c) wv[c] = *(const f32x4*)(wp + c * 4);
        u32x4 o;
#pragma unroll
        for (int c = 0; c < 4; ++c)
            o[c] = pack4(__float2int_rn(wv[c][0] * INV_SW),
                         __float2int_rn(wv[c][1] * INV_SW),
                         __float2int_rn(wv[c][2] * INV_SW),
                         __float2int_rn(wv[c][3] * INV_SW));
        int f  = (v >> 4) * 8 + (k0 >> 6);
        int ln = (v & 15) + 16 * ((k0 >> 4) & 3);
        *(u32x4*)((char*)g_W2i + f * 1024 + ln * 16) = o;
    } else if (b < 464) {
        int gid = (b - 64) * 256 + threadIdx.x;     // 8 elems each
        f32x4 a = *(const f32x4*)(enc + gid * 8);
        f32x4 c = *(const f32x4*)(enc + gid * 8 + 4);
        u32x4 o;
        o[0] = cvt_pk_bf16(fast_tanh(a[0]), fast_tanh(a[1]));
        o[1] = cvt_pk_bf16(fast_tanh(a[2]), fast_tanh(a[3]));
        o[2] = cvt_pk_bf16(fast_tanh(c[0]), fast_tanh(c[1]));
        o[3] = cvt_pk_bf16(fast_tanh(c[2]), fast_tanh(c[3]));
        *(u32x4*)(g_ta + gid * 8) = o;
    } else {
        int gid = (b - 464) * 256 + threadIdx.x;
        f32x4 a = *(const f32x4*)(pred + gid * 8);
        f32x4 c = *(const f32x4*)(pred + gid * 8 + 4);
        u32x4 o;
        o[0] = cvt_pk_bf16(fast_tanh(a[0]), fast_tanh(a[1]));
        o[1] = cvt_pk_bf16(fast_tanh(a[2]), fast_tanh(a[3]));
        o[2] = cvt_pk_bf16(fast_tanh(c[0]), fast_tanh(c[1]));
        o[3] = cvt_pk_bf16(fast_tanh(c[2]), fast_tanh(c[3]));
        *(u32x4*)(g_tp + gid * 8) = o;
    }
}

__global__ __launch_bounds__(512, 4) void joiner_main(
    const float* __restrict__ bias,  // (512,)
    float* __restrict__ out)         // (160000, 512)
{
    __shared__ unsigned char As[BM * Cc];    // 32 KB i8 tile, XOR-swizzled rows

    const int tid = threadIdx.x;

    // ---- bijective XCD-chunked tile remap (8 XCDs, 2500 tiles; q=312,r=4) ----
    const int xcd  = blockIdx.x & 7;
    const int idx  = blockIdx.x >> 3;
    const int tile = (xcd < 4 ? xcd * 313 : 4 * 313 + (xcd - 4) * 312) + idx;

    // ---- stage: A = q127(tanh-sum(ta,tp)) from bf16 tables -> i8 LDS ----
    {
        const int r = tid >> 3;          // 0..63 (tile row)
        const int q = tid & 7;           // k-interleave slot
        const int m  = tile * BM + r;
        const int et = m / 100;
        const int u  = m - et * 100;
        const int bb = m / 40000;
        const int pr = bb * 100 + u;
        const unsigned short* taP = g_ta + et * Cc;
        const unsigned short* tpP = g_tp + pr * Cc;
        char* asB = (char*)As;
        const int swz = (r & 7) << 4;
#pragma unroll
        for (int c = 0; c < 8; ++c) {
            const int k0 = q * 8 + c * 64;      // interleaved chunks: bank-spread
            u16x8 ta8 = *(const u16x8*)(taP + k0);
            u16x8 tp8 = *(const u16x8*)(tpP + k0);
            int qq[8];
#pragma unroll
            for (int j = 0; j < 8; ++j) {
                float a = bf2f(ta8[j]);
                float p = bf2f(tp8[j]);
                float n = (a + p) *
                          __builtin_amdgcn_rcpf(__builtin_fmaf(a, p, 1.0f));
                qq[j] = __float2int_rn(n * 127.0f);
            }
            u32x2 o;
            o[0] = pack4(qq[0], qq[1], qq[2], qq[3]);
            o[1] = pack4(qq[4], qq[5], qq[6], qq[7]);
            int byte = r * 512 + k0;            // i8: 1 byte per elem
            *(u32x2*)(asB + (byte ^ swz)) = o;
        }
    }

    // ---- compute setup ----
    const int lane = tid & 63;
    const int w    = tid >> 6;          // wave -> V slice [w*64, (w+1)*64)
    const int lc   = lane & 15;
    const int lkB  = (lane >> 4) << 4;  // k-byte offset within 64-k step
    const int lr   = (lane >> 4) << 2;

    // B-fragment stream: frag (w*4 + j)*8 + ks, 1KB each
    const char* wb = (const char*)g_W2i + (size_t)(w * 4) * 8 * 1024 + lane * 16;
    const char* asB = (const char*)As;
    const int aswz = (lc & 7) << 4;

    i32x4 bcur[2], bnx[2];
    // prime jb=0 fragments BEFORE the barrier
#pragma unroll
    for (int jj = 0; jj < 2; ++jj)
        bcur[jj] = *(const i32x4*)(wb + ((jj * 8 + 0) << 10));

    __syncthreads();   // only barrier

    // ================= j-half 0 (V cols w*64 + [0,32)) =================
    i32x4 acc[4][2];
#pragma unroll
    for (int i = 0; i < 4; ++i) { acc[i][0] = (i32x4){0,0,0,0}; acc[i][1] = (i32x4){0,0,0,0}; }

#pragma unroll 2
    for (int ks = 0; ks < 8; ++ks) {
        if (ks < 7) {
#pragma unroll
            for (int jj = 0; jj < 2; ++jj)
                bnx[jj] = *(const i32x4*)(wb + ((jj * 8 + ks + 1) << 10));
        }
        i32x4 af[4];
#pragma unroll
        for (int i = 0; i < 4; ++i) {
            int byte = (i * 16 + lc) * 512 + ks * 64 + lkB;
            af[i] = *(const i32x4*)(asB + (byte ^ aswz));
        }
#pragma unroll
        for (int i = 0; i < 4; ++i)
#pragma unroll
            for (int jj = 0; jj < 2; ++jj)
                acc[i][jj] = __builtin_amdgcn_mfma_i32_16x16x64_i8(
                    af[i], bcur[jj], acc[i][jj], 0, 0, 0);
#pragma unroll
        for (int jj = 0; jj < 2; ++jj) bcur[jj] = bnx[jj];
    }

    // prime jb=1 first fragments BEFORE the mid-stores (dodge in-order vmcnt)
#pragma unroll
    for (int jj = 0; jj < 2; ++jj)
        bcur[jj] = *(const i32x4*)(wb + (((2 + jj) * 8 + 0) << 10));

    // ---- mid-epilogue: store j=0,1 now; drain overlaps j-half-1 compute ----
    {
        float b0 = bias[w * 64 + lc];
        float b1 = bias[w * 64 + 16 + lc];
#pragma unroll
        for (int i = 0; i < 4; ++i) {
#pragma unroll
            for (int q = 0; q < 4; ++q) {
                size_t row = (size_t)(tile * BM + i * 16 + lr + q);
                float* op = out + row * Vv + w * 64;
                __builtin_nontemporal_store(
                    __builtin_fmaf((float)acc[i][0][q], OSCALE, b0), op + lc);
                __builtin_nontemporal_store(
                    __builtin_fmaf((float)acc[i][1][q], OSCALE, b1), op + 16 + lc);
            }
        }
    }

    // ================= j-half 1 (V cols w*64 + [32,64)) =================
#pragma unroll
    for (int i = 0; i < 4; ++i) { acc[i][0] = (i32x4){0,0,0,0}; acc[i][1] = (i32x4){0,0,0,0}; }

#pragma unroll 2
    for (int ks = 0; ks < 8; ++ks) {
        if (ks < 7) {
#pragma unroll
            for (int jj = 0; jj < 2; ++jj)
                bnx[jj] = *(const i32x4*)(wb + (((2 + jj) * 8 + ks + 1) << 10));
        }
        i32x4 af[4];
#pragma unroll
        for (int i = 0; i < 4; ++i) {
            int byte = (i * 16 + lc) * 512 + ks * 64 + lkB;
            af[i] = *(const i32x4*)(asB + (byte ^ aswz));
        }
#pragma unroll
        for (int i = 0; i < 4; ++i)
#pragma unroll
            for (int jj = 0; jj < 2; ++jj)
                acc[i][jj] = __builtin_amdgcn_mfma_i32_16x16x64_i8(
                    af[i], bcur[jj], acc[i][jj], 0, 0, 0);
#pragma unroll
        for (int jj = 0; jj < 2; ++jj) bcur[jj] = bnx[jj];
    }

    // ---- final epilogue: store j=2,3 ----
    {
        float b2 = bias[w * 64 + 32 + lc];
        float b3 = bias[w * 64 + 48 + lc];
#pragma unroll
        for (int i = 0; i < 4; ++i) {
#pragma unroll
            for (int q = 0; q < 4; ++q) {
                size_t row = (size_t)(tile * BM + i * 16 + lr + q);
                float* op = out + row * Vv + w * 64;
                __builtin_nontemporal_store(
                    __builtin_fmaf((float)acc[i][0][q], OSCALE, b2), op + 32 + lc);
                __builtin_nontemporal_store(
                    __builtin_fmaf((float)acc[i][1][q], OSCALE, b3), op + 48 + lc);
            }
        }
    }
}

extern "C" void kernel_launch(void* const* d_in, const int* in_sizes, int n_in,
                              void* d_out, int out_size, void* d_ws, size_t ws_size,
                              hipStream_t stream) {
    const float* enc  = (const float*)d_in[0];
    const float* pred = (const float*)d_in[1];
    const float* W    = (const float*)d_in[2];
    const float* bias = (const float*)d_in[3];
    float* out        = (float*)d_out;

    prep_kernel<<<564, 256, 0, stream>>>(W, enc, pred);
    joiner_main<<<NTILE, 512, 0, stream>>>(bias, out);
}